// Round 3
// baseline (477.448 us; speedup 1.0000x reference)
//
#include <hip/hip_runtime.h>

#define N_TOK 131072
#define D_IN  512
#define GHID  64
#define E_EXP 16
#define CAPE  8192
#define H_DIM 128
#define O_DIM 512

typedef __attribute__((ext_vector_type(8))) short bf16x8;
typedef __attribute__((ext_vector_type(4))) float f32x4;

__device__ __forceinline__ ushort f2bf(float f) {
    uint u = __builtin_bit_cast(uint, f);
    u = u + 0x7FFFu + ((u >> 16) & 1u);   // RNE
    return (ushort)(u >> 16);
}

// ---------------- K1: gating (fp32; argmax must be exact vs fp32 ref) ----------------
// 128 tokens/block, 128 threads, 8x8 per-thread tile, K staged in dbuf chunks of 16.
__global__ __launch_bounds__(128) void gating_kernel(
    const float* __restrict__ x, const float* __restrict__ Wg1,
    const float* __restrict__ bg1, const float* __restrict__ Wg2,
    const float* __restrict__ bg2, int* __restrict__ top_expert)
{
    __shared__ float As[2][16][128];   // [buf][k][m] 16 KB
    __shared__ float Bs[2][16][64];    // [buf][k][n] 8 KB
    float (*hst)[128] = reinterpret_cast<float (*)[128]>(&As[0][0][0]);  // [32][128] overlay

    const int tid = threadIdx.x;
    const int m_base = blockIdx.x * 128;
    const int tx = tid & 7, ty = tid >> 3;
    const int m0 = ty * 8, n0 = tx * 8;

    const int bk = tid >> 3, bn = (tid & 7) * 8;   // B-stage mapping

    float acc[8][8] = {};
    float4 av[4], wv[2];

    // prologue: load chunk 0 to regs
    {
        const float4* xp = reinterpret_cast<const float4*>(&x[(size_t)(m_base + tid) * D_IN]);
        av[0] = xp[0]; av[1] = xp[1]; av[2] = xp[2]; av[3] = xp[3];
        const float4* wp = reinterpret_cast<const float4*>(&Wg1[(size_t)bk * GHID + bn]);
        wv[0] = wp[0]; wv[1] = wp[1];
    }
    // write chunk 0 to LDS buf 0
    #pragma unroll
    for (int f = 0; f < 4; ++f) {
        As[0][f*4+0][tid] = av[f].x; As[0][f*4+1][tid] = av[f].y;
        As[0][f*4+2][tid] = av[f].z; As[0][f*4+3][tid] = av[f].w;
    }
    *reinterpret_cast<float4*>(&Bs[0][bk][bn])     = wv[0];
    *reinterpret_cast<float4*>(&Bs[0][bk][bn + 4]) = wv[1];
    __syncthreads();

    for (int c = 0; c < 32; ++c) {
        const int b = c & 1;
        if (c < 31) {   // issue next-chunk loads (latency hides under FMAs)
            const float4* xp = reinterpret_cast<const float4*>(&x[(size_t)(m_base + tid) * D_IN + (c + 1) * 16]);
            av[0] = xp[0]; av[1] = xp[1]; av[2] = xp[2]; av[3] = xp[3];
            const float4* wp = reinterpret_cast<const float4*>(&Wg1[(size_t)((c + 1) * 16 + bk) * GHID + bn]);
            wv[0] = wp[0]; wv[1] = wp[1];
        }
        #pragma unroll
        for (int k = 0; k < 16; ++k) {
            float4 a0 = *reinterpret_cast<const float4*>(&As[b][k][m0]);
            float4 a1 = *reinterpret_cast<const float4*>(&As[b][k][m0 + 4]);
            float4 b0 = *reinterpret_cast<const float4*>(&Bs[b][k][n0]);
            float4 b1 = *reinterpret_cast<const float4*>(&Bs[b][k][n0 + 4]);
            float a[8] = {a0.x,a0.y,a0.z,a0.w,a1.x,a1.y,a1.z,a1.w};
            float bb[8] = {b0.x,b0.y,b0.z,b0.w,b1.x,b1.y,b1.z,b1.w};
            #pragma unroll
            for (int i = 0; i < 8; ++i)
                #pragma unroll
                for (int j = 0; j < 8; ++j)
                    acc[i][j] += a[i] * bb[j];
        }
        if (c < 31) {
            #pragma unroll
            for (int f = 0; f < 4; ++f) {
                As[b^1][f*4+0][tid] = av[f].x; As[b^1][f*4+1][tid] = av[f].y;
                As[b^1][f*4+2][tid] = av[f].z; As[b^1][f*4+3][tid] = av[f].w;
            }
            *reinterpret_cast<float4*>(&Bs[b^1][bk][bn])     = wv[0];
            *reinterpret_cast<float4*>(&Bs[b^1][bk][bn + 4]) = wv[1];
        }
        __syncthreads();
    }

    // epilogue: bias + relu into regs
    float bgv[8];
    {
        const float4* bp = reinterpret_cast<const float4*>(&bg1[n0]);
        float4 q0 = bp[0], q1 = bp[1];
        bgv[0]=q0.x; bgv[1]=q0.y; bgv[2]=q0.z; bgv[3]=q0.w;
        bgv[4]=q1.x; bgv[5]=q1.y; bgv[6]=q1.z; bgv[7]=q1.w;
    }
    #pragma unroll
    for (int i = 0; i < 8; ++i)
        #pragma unroll
        for (int u = 0; u < 8; ++u) {
            float v = acc[i][u] + bgv[u];
            acc[i][u] = v > 0.f ? v : 0.f;
        }

    // layer 2: logits via hst halves (overlay on As), Wg2/bg2 via SGPR (uniform index)
    float lacc[16];
    #pragma unroll
    for (int e = 0; e < 16; ++e) lacc[e] = bg2[e];

    #pragma unroll
    for (int half = 0; half < 2; ++half) {
        if (half == 1) __syncthreads();
        if ((n0 >> 5) == half) {
            #pragma unroll
            for (int u = 0; u < 8; ++u) {
                int j = (n0 + u) & 31;
                float4 w0 = make_float4(acc[0][u], acc[1][u], acc[2][u], acc[3][u]);
                float4 w1 = make_float4(acc[4][u], acc[5][u], acc[6][u], acc[7][u]);
                *reinterpret_cast<float4*>(&hst[j][m0])     = w0;
                *reinterpret_cast<float4*>(&hst[j][m0 + 4]) = w1;
            }
        }
        __syncthreads();
        #pragma unroll 8
        for (int j = 0; j < 32; ++j) {
            float hv = hst[j][tid];
            int jj = half * 32 + j;
            #pragma unroll
            for (int e = 0; e < 16; ++e) lacc[e] += hv * Wg2[jj * 16 + e];
        }
    }

    float best = lacc[0]; int be = 0;
    #pragma unroll
    for (int e = 1; e < 16; ++e) {
        if (lacc[e] > best) { best = lacc[e]; be = e; }
    }
    top_expert[m_base + tid] = be;
}

// ---------------- P1..P3: routing (unchanged) ----------------
__global__ __launch_bounds__(256) void count_kernel(const int* __restrict__ te,
                                                    int* __restrict__ blockCounts)
{
    __shared__ int cnt[16];
    if (threadIdx.x < 16) cnt[threadIdx.x] = 0;
    __syncthreads();
    int base = blockIdx.x * 512;
    for (int i = threadIdx.x; i < 512; i += 256)
        atomicAdd(&cnt[te[base + i]], 1);
    __syncthreads();
    if (threadIdx.x < 16) blockCounts[blockIdx.x * 16 + threadIdx.x] = cnt[threadIdx.x];
}

__global__ void scan_kernel(const int* __restrict__ blockCounts,
                            int* __restrict__ blockOffs, int* __restrict__ totals)
{
    int e = threadIdx.x;
    if (e < 16) {
        int run = 0;
        for (int b = 0; b < 256; ++b) {
            blockOffs[b * 16 + e] = run;
            run += blockCounts[b * 16 + e];
        }
        totals[e] = run;
    }
}

__global__ __launch_bounds__(64) void scatter_kernel(const int* __restrict__ te,
        const int* __restrict__ blockOffs, int* __restrict__ slot_token,
        int* __restrict__ dropCount, int* __restrict__ dropList)
{
    const int b = blockIdx.x;
    const int lane = threadIdx.x;
    int running[16];
    #pragma unroll
    for (int e = 0; e < 16; ++e) running[e] = blockOffs[b * 16 + e];
    const unsigned long long lt = (lane == 0) ? 0ull : ((~0ull) >> (64 - lane));
    const int base = b * 512;
    for (int g = 0; g < 8; ++g) {
        int n = base + g * 64 + lane;
        int e = te[n];
        int p = 0;
        #pragma unroll
        for (int ee = 0; ee < 16; ++ee) {
            unsigned long long bal = __ballot(e == ee);
            if (e == ee) p = running[ee] + __popcll(bal & lt);
            running[ee] += __popcll(bal);
        }
        if (p < CAPE) {
            slot_token[e * CAPE + p] = n;
        } else {
            int di = atomicAdd(dropCount, 1);
            dropList[di] = n;
        }
    }
}

// ---------------- Wc: transpose + fp32->bf16:  in [E][R][C] f32 -> out [E][C][R] bf16 ----------------
template<int R, int C>
__global__ __launch_bounds__(256) void cvt_transpose_kernel(const float* __restrict__ in,
                                                            ushort* __restrict__ out)
{
    __shared__ float s[32][33];
    const int tilesC = C / 32;
    const int tilesR = R / 32;
    int bid = blockIdx.x;
    int e = bid / (tilesR * tilesC);
    int t = bid % (tilesR * tilesC);
    int r0 = (t / tilesC) * 32, c0 = (t % tilesC) * 32;
    const float* ip = in + (size_t)e * R * C;
    ushort* op = out + (size_t)e * C * R;
    int j = threadIdx.x & 31, i0 = threadIdx.x >> 5;
    #pragma unroll
    for (int p = 0; p < 4; ++p) {
        int i = i0 + p * 8;
        s[i][j] = ip[(size_t)(r0 + i) * C + (c0 + j)];
    }
    __syncthreads();
    #pragma unroll
    for (int p = 0; p < 4; ++p) {
        int cc = i0 + p * 8;
        op[(size_t)(c0 + cc) * R + (r0 + j)] = f2bf(s[j][cc]);
    }
}

// ---------------- K4: per-expert MLP + softmax via bf16 MFMA ----------------
// 512 thr = 8 waves (2M x 4N), 64 tokens/block; W1T[e][h][d], W2T[e][o][h] bf16 from L2.
__global__ __launch_bounds__(512, 4) void expert_mfma_kernel(
    const float* __restrict__ x,
    const ushort* __restrict__ W1T, const float* __restrict__ b1,
    const ushort* __restrict__ W2T, const float* __restrict__ b2,
    const int* __restrict__ slot_token, const int* __restrict__ totals,
    float* __restrict__ out)
{
    __shared__ ushort xs_u[64 * 512];    // 64 KB; first 16 KB reused for h after phase 1
    __shared__ int    toks[64];
    __shared__ float  redm[4][64];
    __shared__ float  reds[4][64];

    const int tid  = threadIdx.x;
    const int e    = blockIdx.x >> 7;       // 128 blocks/expert
    const int sb   = blockIdx.x & 127;
    const int slot0 = sb * 64;
    int vc = totals[e]; if (vc > CAPE) vc = CAPE;
    if (slot0 >= vc) return;
    int nt = vc - slot0; if (nt > 64) nt = 64;

    const int lane = tid & 63;
    const int wid  = tid >> 6;
    const int wm   = wid & 1;              // M-group (32 rows)
    const int wn   = wid >> 1;             // N-group (0..3)
    const int l15  = lane & 15;
    const int l4   = lane >> 4;

    if (tid < 64) toks[tid] = (tid < nt) ? slot_token[e * CAPE + slot0 + tid] : -1;
    __syncthreads();

    char* xsb = (char*)xs_u;

    // ---- stage x rows: f32 global -> bf16 swizzled LDS (row stride 1024 B) ----
    #pragma unroll
    for (int it = 0; it < 8; ++it) {
        int g = it * 512 + tid;            // 8-float group index 0..4095
        int row = g >> 6, cg = g & 63;
        int tk = toks[row];
        float f[8];
        if (tk >= 0) {
            const float4* xp = reinterpret_cast<const float4*>(&x[(size_t)tk * D_IN + cg * 8]);
            float4 v0 = xp[0], v1 = xp[1];
            f[0]=v0.x; f[1]=v0.y; f[2]=v0.z; f[3]=v0.w;
            f[4]=v1.x; f[5]=v1.y; f[6]=v1.z; f[7]=v1.w;
        } else {
            #pragma unroll
            for (int q = 0; q < 8; ++q) f[q] = 0.f;
        }
        union { bf16x8 v; ushort u[8]; } w;
        #pragma unroll
        for (int q = 0; q < 8; ++q) w.u[q] = f2bf(f[q]);
        *reinterpret_cast<bf16x8*>(xsb + row * 1024 + ((cg * 16) ^ ((row & 7) << 4))) = w.v;
    }
    __syncthreads();

    // ---- phase 1: h = relu(x @ W1 + b1); wave = 32 rows x 32 cols ----
    f32x4 acc1[2][2] = {};
    {
        const int r0 = wm * 32 + l15;      // fi adds 16
        const ushort* w1p = W1T + ((size_t)e * H_DIM + wn * 32 + l15) * D_IN + l4 * 8;
        #pragma unroll 4
        for (int kt = 0; kt < 512; kt += 32) {
            int r = r0;
            bf16x8 a0 = *reinterpret_cast<const bf16x8*>(xsb + r * 1024 + ((kt * 2 + l4 * 16) ^ ((r & 7) << 4)));
            r = r0 + 16;
            bf16x8 a1 = *reinterpret_cast<const bf16x8*>(xsb + r * 1024 + ((kt * 2 + l4 * 16) ^ ((r & 7) << 4)));
            bf16x8 b0 = *reinterpret_cast<const bf16x8*>(w1p + kt);
            bf16x8 b1v = *reinterpret_cast<const bf16x8*>(w1p + 16 * D_IN + kt);
            acc1[0][0] = __builtin_amdgcn_mfma_f32_16x16x32_bf16(a0, b0,  acc1[0][0], 0, 0, 0);
            acc1[0][1] = __builtin_amdgcn_mfma_f32_16x16x32_bf16(a0, b1v, acc1[0][1], 0, 0, 0);
            acc1[1][0] = __builtin_amdgcn_mfma_f32_16x16x32_bf16(a1, b0,  acc1[1][0], 0, 0, 0);
            acc1[1][1] = __builtin_amdgcn_mfma_f32_16x16x32_bf16(a1, b1v, acc1[1][1], 0, 0, 0);
        }
    }
    __syncthreads();   // all xs reads complete

    // ---- write h to LDS (overlay on xs region; row stride 256 B, swizzled) ----
    {
        char* hbb = xsb;
        #pragma unroll
        for (int fj = 0; fj < 2; ++fj) {
            int col = wn * 32 + fj * 16 + l15;
            float bv = b1[e * H_DIM + col];
            #pragma unroll
            for (int fi = 0; fi < 2; ++fi) {
                #pragma unroll
                for (int j = 0; j < 4; ++j) {
                    int row = wm * 32 + fi * 16 + l4 * 4 + j;
                    float v = acc1[fi][fj][j] + bv;
                    v = v > 0.f ? v : 0.f;
                    *reinterpret_cast<ushort*>(hbb + row * 256 + ((col * 2) ^ ((row & 7) << 4))) = f2bf(v);
                }
            }
        }
    }
    __syncthreads();

    // ---- phase 2: logits = h @ W2 + b2; wave = 32 rows x 128 cols ----
    f32x4 acc2[2][8] = {};
    {
        char* hbb = xsb;
        const int r0 = wm * 32 + l15;
        const ushort* w2p = W2T + ((size_t)e * O_DIM + wn * 128 + l15) * H_DIM + l4 * 8;
        #pragma unroll
        for (int kt = 0; kt < 128; kt += 32) {
            int r = r0;
            bf16x8 a0 = *reinterpret_cast<const bf16x8*>(hbb + r * 256 + ((kt * 2 + l4 * 16) ^ ((r & 7) << 4)));
            r = r0 + 16;
            bf16x8 a1 = *reinterpret_cast<const bf16x8*>(hbb + r * 256 + ((kt * 2 + l4 * 16) ^ ((r & 7) << 4)));
            #pragma unroll
            for (int f = 0; f < 8; ++f) {
                bf16x8 b = *reinterpret_cast<const bf16x8*>(w2p + f * 16 * H_DIM + kt);
                acc2[0][f] = __builtin_amdgcn_mfma_f32_16x16x32_bf16(a0, b, acc2[0][f], 0, 0, 0);
                acc2[1][f] = __builtin_amdgcn_mfma_f32_16x16x32_bf16(a1, b, acc2[1][f], 0, 0, 0);
            }
        }
    }
    // + bias
    #pragma unroll
    for (int f = 0; f < 8; ++f) {
        float bv = b2[e * O_DIM + wn * 128 + f * 16 + l15];
        #pragma unroll
        for (int fi = 0; fi < 2; ++fi)
            #pragma unroll
            for (int j = 0; j < 4; ++j) acc2[fi][f][j] += bv;
    }

    // ---- softmax over 512 cols (4 wn-waves hold 128 each) ----
    #pragma unroll
    for (int fi = 0; fi < 2; ++fi)
        #pragma unroll
        for (int j = 0; j < 4; ++j) {
            float m = acc2[fi][0][j];
            #pragma unroll
            for (int f = 1; f < 8; ++f) m = fmaxf(m, acc2[fi][f][j]);
            #pragma unroll
            for (int msk = 1; msk < 16; msk <<= 1) m = fmaxf(m, __shfl_xor(m, msk, 64));
            if (l15 == 0) redm[wn][wm * 32 + fi * 16 + l4 * 4 + j] = m;
        }
    __syncthreads();
    #pragma unroll
    for (int fi = 0; fi < 2; ++fi)
        #pragma unroll
        for (int j = 0; j < 4; ++j) {
            int r = wm * 32 + fi * 16 + l4 * 4 + j;
            float M = fmaxf(fmaxf(redm[0][r], redm[1][r]), fmaxf(redm[2][r], redm[3][r]));
            float s = 0.f;
            #pragma unroll
            for (int f = 0; f < 8; ++f) {
                float ex = expf(acc2[fi][f][j] - M);
                acc2[fi][f][j] = ex;
                s += ex;
            }
            #pragma unroll
            for (int msk = 1; msk < 16; msk <<= 1) s += __shfl_xor(s, msk, 64);
            if (l15 == 0) reds[wn][r] = s;
        }
    __syncthreads();
    #pragma unroll
    for (int fi = 0; fi < 2; ++fi)
        #pragma unroll
        for (int j = 0; j < 4; ++j) {
            int r = wm * 32 + fi * 16 + l4 * 4 + j;
            int tk = toks[r];
            if (tk < 0) continue;
            float inv = 1.f / (reds[0][r] + reds[1][r] + reds[2][r] + reds[3][r]);
            float* orow = out + (size_t)tk * O_DIM + wn * 128 + l15;
            #pragma unroll
            for (int f = 0; f < 8; ++f) orow[f * 16] = acc2[fi][f][j] * inv;
        }
}

// ---------------- K5: zero rows of dropped tokens ----------------
__global__ __launch_bounds__(256) void zero_dropped_kernel(const int* __restrict__ dropCount,
        const int* __restrict__ dropList, float* __restrict__ out)
{
    int cnt = *dropCount;
    for (int i = blockIdx.x; i < cnt; i += gridDim.x) {
        int n = dropList[i];
        reinterpret_cast<float2*>(&out[(size_t)n * O_DIM])[threadIdx.x] = make_float2(0.f, 0.f);
    }
}

extern "C" void kernel_launch(void* const* d_in, const int* in_sizes, int n_in,
                              void* d_out, int out_size, void* d_ws, size_t ws_size,
                              hipStream_t stream) {
    (void)in_sizes; (void)n_in; (void)out_size; (void)ws_size;
    const float* x   = (const float*)d_in[0];
    const float* Wg1 = (const float*)d_in[1];
    const float* bg1 = (const float*)d_in[2];
    const float* Wg2 = (const float*)d_in[3];
    const float* bg2 = (const float*)d_in[4];
    const float* W1  = (const float*)d_in[5];
    const float* b1  = (const float*)d_in[6];
    const float* W2  = (const float*)d_in[7];
    const float* b2  = (const float*)d_in[8];
    float* out = (float*)d_out;

    char* ws = (char*)d_ws;
    size_t off = 0;
    int* dropCount   = (int*)(ws + off); off += 256;
    int* top_expert  = (int*)(ws + off); off += (size_t)N_TOK * 4;
    int* blockCounts = (int*)(ws + off); off += 256 * 16 * 4;
    int* blockOffs   = (int*)(ws + off); off += 256 * 16 * 4;
    int* totals      = (int*)(ws + off); off += 256;
    int* slot_token  = (int*)(ws + off); off += (size_t)E_EXP * CAPE * 4;
    int* dropList    = (int*)(ws + off); off += (size_t)N_TOK * 4;
    ushort* W1T      = (ushort*)(ws + off); off += (size_t)E_EXP * D_IN * H_DIM * 2;
    ushort* W2T      = (ushort*)(ws + off); off += (size_t)E_EXP * H_DIM * O_DIM * 2;

    hipMemsetAsync(dropCount, 0, 4, stream);
    cvt_transpose_kernel<D_IN, H_DIM><<<E_EXP * (D_IN/32) * (H_DIM/32), 256, 0, stream>>>(W1, W1T);
    cvt_transpose_kernel<H_DIM, O_DIM><<<E_EXP * (H_DIM/32) * (O_DIM/32), 256, 0, stream>>>(W2, W2T);
    gating_kernel<<<N_TOK / 128, 128, 0, stream>>>(x, Wg1, bg1, Wg2, bg2, top_expert);
    count_kernel<<<N_TOK / 512, 256, 0, stream>>>(top_expert, blockCounts);
    scan_kernel<<<1, 64, 0, stream>>>(blockCounts, blockOffs, totals);
    scatter_kernel<<<N_TOK / 512, 64, 0, stream>>>(top_expert, blockOffs, slot_token, dropCount, dropList);
    expert_mfma_kernel<<<E_EXP * (CAPE / 64), 512, 0, stream>>>(x, W1T, b1, W2T, b2, slot_token, totals, out);
    zero_dropped_kernel<<<256, 256, 0, stream>>>(dropCount, dropList, out);
}

// Round 4
// 385.709 us; speedup vs baseline: 1.2378x; 1.2378x over previous
//
#include <hip/hip_runtime.h>

#define N_TOK 131072
#define D_IN  512
#define GHID  64
#define E_EXP 16
#define CAPE  8192
#define H_DIM 128
#define O_DIM 512

typedef __attribute__((ext_vector_type(8))) short bf16x8;
typedef __attribute__((ext_vector_type(4))) float f32x4;

__device__ __forceinline__ ushort f2bf(float f) {
    uint u = __builtin_bit_cast(uint, f);
    u = u + 0x7FFFu + ((u >> 16) & 1u);   // RNE
    return (ushort)(u >> 16);
}
__device__ __forceinline__ float bf2f(ushort s) {
    return __builtin_bit_cast(float, ((uint)s) << 16);
}

// ---------------- Wsplit: Wg1 [512][64] f32 -> WgT[3][64][512] bf16 planes ----------------
__global__ __launch_bounds__(64) void wsplit_kernel(const float* __restrict__ Wg1,
                                                    ushort* __restrict__ WgT)
{
    int n = blockIdx.x;                  // 0..63
    for (int k = threadIdx.x; k < 512; k += 64) {
        float v = Wg1[(size_t)k * GHID + n];
        ushort s0 = f2bf(v); float r1 = v - bf2f(s0);
        ushort s1 = f2bf(r1); float r2 = r1 - bf2f(s1);
        ushort s2 = f2bf(r2);
        WgT[(size_t)(0 * 64 + n) * 512 + k] = s0;
        WgT[(size_t)(1 * 64 + n) * 512 + k] = s1;
        WgT[(size_t)(2 * 64 + n) * 512 + k] = s2;
    }
}

// ---------------- K1: gating via exact 3-plane bf16-split MFMA ----------------
// 64 tokens/block, 256 thr = 4 waves (2M x 2N). K dbuf chunks of 64.
// Also emits xbf = bf16(x) for the expert kernel (if non-null).
__global__ __launch_bounds__(256, 4) void gating_mfma_kernel(
    const float* __restrict__ x, const ushort* __restrict__ WgT,
    const float* __restrict__ bg1, const float* __restrict__ Wg2,
    const float* __restrict__ bg2, int* __restrict__ top_expert,
    ushort* __restrict__ xbf)
{
    __shared__ ushort xsp[2][3][64][64];   // [buf][plane][row][k], swizzled 128B rows; 48 KB
    __shared__ float  hs[64][65];          // 16.6 KB

    const int tid = threadIdx.x;
    const int m_base = blockIdx.x * 64;
    const int lane = tid & 63, wid = tid >> 6;
    const int l15 = lane & 15, l4 = lane >> 4;
    const int wm = wid & 1, wn = wid >> 1;   // wave = 32 rows x 32 cols

    // staging mapping: row = tid>>2 (0..63), kq = (tid&3)*16 floats
    const int srow = tid >> 2, skq = (tid & 3) * 16;
    const int sswz = (srow & 7) << 4;
    char* xb = (char*)xsp;
    const size_t plane_stride = 64 * 128;              // bytes per [row][k] plane
    char* srow_base = xb + (size_t)srow * 128;

    float4 av[4];
    const float* xrow = &x[(size_t)(m_base + srow) * D_IN];

    // helper lambdas (inlined manually):
    // --- prologue: chunk 0 ---
    {
        const float4* xp = reinterpret_cast<const float4*>(xrow + skq);
        av[0] = xp[0]; av[1] = xp[1]; av[2] = xp[2]; av[3] = xp[3];
    }
    {
        float f[16];
        #pragma unroll
        for (int q = 0; q < 4; ++q) {
            f[q*4+0] = av[q].x; f[q*4+1] = av[q].y; f[q*4+2] = av[q].z; f[q*4+3] = av[q].w;
        }
        union { bf16x8 v[2]; ushort u[16]; } p0, p1, p2;
        #pragma unroll
        for (int q = 0; q < 16; ++q) {
            float v = f[q];
            ushort s0 = f2bf(v); float r1 = v - bf2f(s0);
            ushort s1 = f2bf(r1); float r2 = r1 - bf2f(s1);
            ushort s2 = f2bf(r2);
            p0.u[q] = s0; p1.u[q] = s1; p2.u[q] = s2;
        }
        #pragma unroll
        for (int h = 0; h < 2; ++h) {
            int boff = (skq * 2 + h * 16) ^ sswz;
            *reinterpret_cast<bf16x8*>(srow_base + 0 * 3 * plane_stride + 0 * plane_stride + boff) = p0.v[h];
            *reinterpret_cast<bf16x8*>(srow_base + 0 * 3 * plane_stride + 1 * plane_stride + boff) = p1.v[h];
            *reinterpret_cast<bf16x8*>(srow_base + 0 * 3 * plane_stride + 2 * plane_stride + boff) = p2.v[h];
        }
        if (xbf) {
            ushort* op = &xbf[(size_t)(m_base + srow) * D_IN + skq];
            *reinterpret_cast<bf16x8*>(op)     = p0.v[0];
            *reinterpret_cast<bf16x8*>(op + 8) = p0.v[1];
        }
    }
    __syncthreads();

    f32x4 acc[2][2] = {};
    const int arow0 = wm * 32 + l15;

    for (int kc = 0; kc < 8; ++kc) {
        const int b = kc & 1;
        if (kc < 7) {
            const float4* xp = reinterpret_cast<const float4*>(xrow + (kc + 1) * 64 + skq);
            av[0] = xp[0]; av[1] = xp[1]; av[2] = xp[2]; av[3] = xp[3];
        }
        // compute chunk kc from buf b
        char* bufb = xb + (size_t)b * 3 * plane_stride;
        #pragma unroll
        for (int ks = 0; ks < 2; ++ks) {
            bf16x8 a0[2], a1[2], a2[2];
            #pragma unroll
            for (int fi = 0; fi < 2; ++fi) {
                int r = arow0 + fi * 16;
                int boff = (ks * 64 + l4 * 16) ^ ((r & 7) << 4);
                char* rb = bufb + (size_t)r * 128;
                a0[fi] = *reinterpret_cast<const bf16x8*>(rb + 0 * plane_stride + boff);
                a1[fi] = *reinterpret_cast<const bf16x8*>(rb + 1 * plane_stride + boff);
                a2[fi] = *reinterpret_cast<const bf16x8*>(rb + 2 * plane_stride + boff);
            }
            #pragma unroll
            for (int fj = 0; fj < 2; ++fj) {
                int col = wn * 32 + fj * 16 + l15;
                const ushort* bp = WgT + (size_t)col * 512 + kc * 64 + ks * 32 + l4 * 8;
                bf16x8 b0 = *reinterpret_cast<const bf16x8*>(bp);
                bf16x8 b1 = *reinterpret_cast<const bf16x8*>(bp + 64 * 512);
                bf16x8 b2 = *reinterpret_cast<const bf16x8*>(bp + 2 * 64 * 512);
                #pragma unroll
                for (int fi = 0; fi < 2; ++fi) {
                    acc[fi][fj] = __builtin_amdgcn_mfma_f32_16x16x32_bf16(a0[fi], b0, acc[fi][fj], 0, 0, 0);
                    acc[fi][fj] = __builtin_amdgcn_mfma_f32_16x16x32_bf16(a0[fi], b1, acc[fi][fj], 0, 0, 0);
                    acc[fi][fj] = __builtin_amdgcn_mfma_f32_16x16x32_bf16(a1[fi], b0, acc[fi][fj], 0, 0, 0);
                    acc[fi][fj] = __builtin_amdgcn_mfma_f32_16x16x32_bf16(a0[fi], b2, acc[fi][fj], 0, 0, 0);
                    acc[fi][fj] = __builtin_amdgcn_mfma_f32_16x16x32_bf16(a1[fi], b1, acc[fi][fj], 0, 0, 0);
                    acc[fi][fj] = __builtin_amdgcn_mfma_f32_16x16x32_bf16(a2[fi], b0, acc[fi][fj], 0, 0, 0);
                }
            }
        }
        if (kc < 7) {
            float f[16];
            #pragma unroll
            for (int q = 0; q < 4; ++q) {
                f[q*4+0] = av[q].x; f[q*4+1] = av[q].y; f[q*4+2] = av[q].z; f[q*4+3] = av[q].w;
            }
            union { bf16x8 v[2]; ushort u[16]; } p0, p1, p2;
            #pragma unroll
            for (int q = 0; q < 16; ++q) {
                float v = f[q];
                ushort s0 = f2bf(v); float r1 = v - bf2f(s0);
                ushort s1 = f2bf(r1); float r2 = r1 - bf2f(s1);
                ushort s2 = f2bf(r2);
                p0.u[q] = s0; p1.u[q] = s1; p2.u[q] = s2;
            }
            char* dst = srow_base + (size_t)(b ^ 1) * 3 * plane_stride;
            #pragma unroll
            for (int h = 0; h < 2; ++h) {
                int boff = (skq * 2 + h * 16) ^ sswz;
                *reinterpret_cast<bf16x8*>(dst + 0 * plane_stride + boff) = p0.v[h];
                *reinterpret_cast<bf16x8*>(dst + 1 * plane_stride + boff) = p1.v[h];
                *reinterpret_cast<bf16x8*>(dst + 2 * plane_stride + boff) = p2.v[h];
            }
            if (xbf) {
                ushort* op = &xbf[(size_t)(m_base + srow) * D_IN + (kc + 1) * 64 + skq];
                *reinterpret_cast<bf16x8*>(op)     = p0.v[0];
                *reinterpret_cast<bf16x8*>(op + 8) = p0.v[1];
            }
        }
        __syncthreads();
    }

    // epilogue: bias + relu -> hs
    #pragma unroll
    for (int fj = 0; fj < 2; ++fj) {
        int col = wn * 32 + fj * 16 + l15;
        float bv = bg1[col];
        #pragma unroll
        for (int fi = 0; fi < 2; ++fi) {
            #pragma unroll
            for (int j = 0; j < 4; ++j) {
                int row = wm * 32 + fi * 16 + l4 * 4 + j;
                float v = acc[fi][fj][j] + bv;
                hs[row][col] = v > 0.f ? v : 0.f;
            }
        }
    }
    __syncthreads();

    // layer 2 + argmax (fp32, same accumulation order as proven rounds)
    if (tid < 64) {
        float lacc[16];
        #pragma unroll
        for (int e = 0; e < 16; ++e) lacc[e] = bg2[e];
        #pragma unroll 8
        for (int k = 0; k < 64; ++k) {
            float hv = hs[tid][k];
            #pragma unroll
            for (int e = 0; e < 16; ++e) lacc[e] += hv * Wg2[k * 16 + e];
        }
        float best = lacc[0]; int be = 0;
        #pragma unroll
        for (int e = 1; e < 16; ++e) {
            if (lacc[e] > best) { best = lacc[e]; be = e; }
        }
        top_expert[m_base + tid] = be;
    }
}

// ---------------- P1..P3: routing (unchanged) ----------------
__global__ __launch_bounds__(256) void count_kernel(const int* __restrict__ te,
                                                    int* __restrict__ blockCounts)
{
    __shared__ int cnt[16];
    if (threadIdx.x < 16) cnt[threadIdx.x] = 0;
    __syncthreads();
    int base = blockIdx.x * 512;
    for (int i = threadIdx.x; i < 512; i += 256)
        atomicAdd(&cnt[te[base + i]], 1);
    __syncthreads();
    if (threadIdx.x < 16) blockCounts[blockIdx.x * 16 + threadIdx.x] = cnt[threadIdx.x];
}

__global__ void scan_kernel(const int* __restrict__ blockCounts,
                            int* __restrict__ blockOffs, int* __restrict__ totals)
{
    int e = threadIdx.x;
    if (e < 16) {
        int run = 0;
        for (int b = 0; b < 256; ++b) {
            blockOffs[b * 16 + e] = run;
            run += blockCounts[b * 16 + e];
        }
        totals[e] = run;
    }
}

__global__ __launch_bounds__(64) void scatter_kernel(const int* __restrict__ te,
        const int* __restrict__ blockOffs, int* __restrict__ slot_token,
        int* __restrict__ dropCount, int* __restrict__ dropList)
{
    const int b = blockIdx.x;
    const int lane = threadIdx.x;
    int running[16];
    #pragma unroll
    for (int e = 0; e < 16; ++e) running[e] = blockOffs[b * 16 + e];
    const unsigned long long lt = (lane == 0) ? 0ull : ((~0ull) >> (64 - lane));
    const int base = b * 512;
    for (int g = 0; g < 8; ++g) {
        int n = base + g * 64 + lane;
        int e = te[n];
        int p = 0;
        #pragma unroll
        for (int ee = 0; ee < 16; ++ee) {
            unsigned long long bal = __ballot(e == ee);
            if (e == ee) p = running[ee] + __popcll(bal & lt);
            running[ee] += __popcll(bal);
        }
        if (p < CAPE) {
            slot_token[e * CAPE + p] = n;
        } else {
            int di = atomicAdd(dropCount, 1);
            dropList[di] = n;
        }
    }
}

// ---------------- Wc: transpose + fp32->bf16:  in [E][R][C] f32 -> out [E][C][R] bf16 ----------------
template<int R, int C>
__global__ __launch_bounds__(256) void cvt_transpose_kernel(const float* __restrict__ in,
                                                            ushort* __restrict__ out)
{
    __shared__ float s[32][33];
    const int tilesC = C / 32;
    const int tilesR = R / 32;
    int bid = blockIdx.x;
    int e = bid / (tilesR * tilesC);
    int t = bid % (tilesR * tilesC);
    int r0 = (t / tilesC) * 32, c0 = (t % tilesC) * 32;
    const float* ip = in + (size_t)e * R * C;
    ushort* op = out + (size_t)e * C * R;
    int j = threadIdx.x & 31, i0 = threadIdx.x >> 5;
    #pragma unroll
    for (int p = 0; p < 4; ++p) {
        int i = i0 + p * 8;
        s[i][j] = ip[(size_t)(r0 + i) * C + (c0 + j)];
    }
    __syncthreads();
    #pragma unroll
    for (int p = 0; p < 4; ++p) {
        int cc = i0 + p * 8;
        op[(size_t)(c0 + cc) * R + (r0 + j)] = f2bf(s[j][cc]);
    }
}

// ---------------- K4: per-expert MLP + softmax via bf16 MFMA ----------------
// 512 thr = 8 waves; wave = 64 rows x (16 cols phase1 / 64 cols phase2) -> no duplicate B loads.
__global__ __launch_bounds__(512, 4) void expert_mfma_kernel(
    const float* __restrict__ x, const ushort* __restrict__ xbf,
    const ushort* __restrict__ W1T, const float* __restrict__ b1,
    const ushort* __restrict__ W2T, const float* __restrict__ b2,
    const int* __restrict__ slot_token, const int* __restrict__ totals,
    float* __restrict__ out)
{
    __shared__ ushort xs_u[64 * 512];    // 64 KB; first 16 KB reused for h after phase 1
    __shared__ int    toks[64];
    __shared__ float  redm[8][64];
    __shared__ float  reds[8][64];

    const int tid  = threadIdx.x;
    const int e    = blockIdx.x >> 7;       // 128 blocks/expert
    const int sb   = blockIdx.x & 127;
    const int slot0 = sb * 64;
    int vc = totals[e]; if (vc > CAPE) vc = CAPE;
    if (slot0 >= vc) return;
    int nt = vc - slot0; if (nt > 64) nt = 64;

    const int lane = tid & 63;
    const int wid  = tid >> 6;             // 0..7
    const int l15  = lane & 15;
    const int l4   = lane >> 4;

    if (tid < 64) toks[tid] = (tid < nt) ? slot_token[e * CAPE + slot0 + tid] : -1;
    __syncthreads();

    char* xsb = (char*)xs_u;

    // ---- stage x rows into swizzled bf16 LDS (row stride 1024 B) ----
    if (xbf) {
        #pragma unroll
        for (int it = 0; it < 8; ++it) {
            int g = it * 512 + tid;        // 8-elem group 0..4095
            int row = g >> 6, cg = g & 63;
            int tk = toks[row];
            bf16x8 v = {};
            if (tk >= 0) v = *reinterpret_cast<const bf16x8*>(&xbf[(size_t)tk * D_IN + cg * 8]);
            *reinterpret_cast<bf16x8*>(xsb + row * 1024 + ((cg * 16) ^ ((row & 7) << 4))) = v;
        }
    } else {
        #pragma unroll
        for (int it = 0; it < 8; ++it) {
            int g = it * 512 + tid;
            int row = g >> 6, cg = g & 63;
            int tk = toks[row];
            float f[8];
            if (tk >= 0) {
                const float4* xp = reinterpret_cast<const float4*>(&x[(size_t)tk * D_IN + cg * 8]);
                float4 v0 = xp[0], v1 = xp[1];
                f[0]=v0.x; f[1]=v0.y; f[2]=v0.z; f[3]=v0.w;
                f[4]=v1.x; f[5]=v1.y; f[6]=v1.z; f[7]=v1.w;
            } else {
                #pragma unroll
                for (int q = 0; q < 8; ++q) f[q] = 0.f;
            }
            union { bf16x8 v; ushort u[8]; } w;
            #pragma unroll
            for (int q = 0; q < 8; ++q) w.u[q] = f2bf(f[q]);
            *reinterpret_cast<bf16x8*>(xsb + row * 1024 + ((cg * 16) ^ ((row & 7) << 4))) = w.v;
        }
    }
    __syncthreads();

    // ---- phase 1: h = relu(x @ W1 + b1); wave = 64 rows x 16 cols ----
    f32x4 acc1[4] = {};
    {
        const ushort* w1p = W1T + ((size_t)e * H_DIM + wid * 16 + l15) * D_IN + l4 * 8;
        #pragma unroll 4
        for (int kt = 0; kt < 512; kt += 32) {
            bf16x8 bfrag = *reinterpret_cast<const bf16x8*>(w1p + kt);
            #pragma unroll
            for (int fi = 0; fi < 4; ++fi) {
                int r = fi * 16 + l15;
                bf16x8 a = *reinterpret_cast<const bf16x8*>(xsb + r * 1024 + ((kt * 2 + l4 * 16) ^ ((r & 7) << 4)));
                acc1[fi] = __builtin_amdgcn_mfma_f32_16x16x32_bf16(a, bfrag, acc1[fi], 0, 0, 0);
            }
        }
    }
    __syncthreads();   // all xs reads complete before h overlay

    // ---- write h (bf16, swizzled, row stride 256 B) overlaying xs ----
    {
        int col = wid * 16 + l15;
        float bv = b1[e * H_DIM + col];
        #pragma unroll
        for (int fi = 0; fi < 4; ++fi) {
            #pragma unroll
            for (int j = 0; j < 4; ++j) {
                int row = fi * 16 + l4 * 4 + j;
                float v = acc1[fi][j] + bv;
                v = v > 0.f ? v : 0.f;
                *reinterpret_cast<ushort*>(xsb + row * 256 + ((col * 2) ^ ((row & 7) << 4))) = f2bf(v);
            }
        }
    }
    __syncthreads();

    // ---- phase 2: logits = h @ W2 + b2; wave = 64 rows x 64 cols ----
    f32x4 acc2[4][4] = {};
    {
        const ushort* w2p = W2T + ((size_t)e * O_DIM + wid * 64 + l15) * H_DIM + l4 * 8;
        #pragma unroll
        for (int kt = 0; kt < 128; kt += 32) {
            bf16x8 a[4];
            #pragma unroll
            for (int fi = 0; fi < 4; ++fi) {
                int r = fi * 16 + l15;
                a[fi] = *reinterpret_cast<const bf16x8*>(xsb + r * 256 + ((kt * 2 + l4 * 16) ^ ((r & 7) << 4)));
            }
            #pragma unroll
            for (int fj = 0; fj < 4; ++fj) {
                bf16x8 bfrag = *reinterpret_cast<const bf16x8*>(w2p + (size_t)fj * 16 * H_DIM + kt);
                #pragma unroll
                for (int fi = 0; fi < 4; ++fi)
                    acc2[fi][fj] = __builtin_amdgcn_mfma_f32_16x16x32_bf16(a[fi], bfrag, acc2[fi][fj], 0, 0, 0);
            }
        }
    }
    // + bias
    #pragma unroll
    for (int fj = 0; fj < 4; ++fj) {
        float bv = b2[e * O_DIM + wid * 64 + fj * 16 + l15];
        #pragma unroll
        for (int fi = 0; fi < 4; ++fi)
            #pragma unroll
            for (int j = 0; j < 4; ++j) acc2[fi][fj][j] += bv;
    }

    // ---- softmax over 512 cols (8 waves hold 64 each) ----
    #pragma unroll
    for (int fi = 0; fi < 4; ++fi)
        #pragma unroll
        for (int j = 0; j < 4; ++j) {
            float m = acc2[fi][0][j];
            #pragma unroll
            for (int fj = 1; fj < 4; ++fj) m = fmaxf(m, acc2[fi][fj][j]);
            #pragma unroll
            for (int msk = 1; msk < 16; msk <<= 1) m = fmaxf(m, __shfl_xor(m, msk, 64));
            if (l15 == 0) redm[wid][fi * 16 + l4 * 4 + j] = m;
        }
    __syncthreads();
    #pragma unroll
    for (int fi = 0; fi < 4; ++fi)
        #pragma unroll
        for (int j = 0; j < 4; ++j) {
            int r = fi * 16 + l4 * 4 + j;
            float M = redm[0][r];
            #pragma unroll
            for (int w = 1; w < 8; ++w) M = fmaxf(M, redm[w][r]);
            float s = 0.f;
            #pragma unroll
            for (int fj = 0; fj < 4; ++fj) {
                float ex = expf(acc2[fi][fj][j] - M);
                acc2[fi][fj][j] = ex;
                s += ex;
            }
            #pragma unroll
            for (int msk = 1; msk < 16; msk <<= 1) s += __shfl_xor(s, msk, 64);
            if (l15 == 0) reds[wid][r] = s;
        }
    __syncthreads();
    #pragma unroll
    for (int fi = 0; fi < 4; ++fi)
        #pragma unroll
        for (int j = 0; j < 4; ++j) {
            int r = fi * 16 + l4 * 4 + j;
            int tk = toks[r];
            if (tk < 0) continue;
            float S = reds[0][r];
            #pragma unroll
            for (int w = 1; w < 8; ++w) S += reds[w][r];
            float inv = 1.f / S;
            float* orow = out + (size_t)tk * O_DIM + wid * 64 + l15;
            #pragma unroll
            for (int fj = 0; fj < 4; ++fj) orow[fj * 16] = acc2[fi][fj][j] * inv;
        }
}

// ---------------- K5: zero rows of dropped tokens ----------------
__global__ __launch_bounds__(256) void zero_dropped_kernel(const int* __restrict__ dropCount,
        const int* __restrict__ dropList, float* __restrict__ out)
{
    int cnt = *dropCount;
    for (int i = blockIdx.x; i < cnt; i += gridDim.x) {
        int n = dropList[i];
        reinterpret_cast<float2*>(&out[(size_t)n * O_DIM])[threadIdx.x] = make_float2(0.f, 0.f);
    }
}

extern "C" void kernel_launch(void* const* d_in, const int* in_sizes, int n_in,
                              void* d_out, int out_size, void* d_ws, size_t ws_size,
                              hipStream_t stream) {
    (void)in_sizes; (void)n_in; (void)out_size;
    const float* x   = (const float*)d_in[0];
    const float* Wg1 = (const float*)d_in[1];
    const float* bg1 = (const float*)d_in[2];
    const float* Wg2 = (const float*)d_in[3];
    const float* bg2 = (const float*)d_in[4];
    const float* W1  = (const float*)d_in[5];
    const float* b1  = (const float*)d_in[6];
    const float* W2  = (const float*)d_in[7];
    const float* b2  = (const float*)d_in[8];
    float* out = (float*)d_out;

    char* ws = (char*)d_ws;
    size_t off = 0;
    int* dropCount   = (int*)(ws + off); off += 256;
    int* top_expert  = (int*)(ws + off); off += (size_t)N_TOK * 4;
    int* blockCounts = (int*)(ws + off); off += 256 * 16 * 4;
    int* blockOffs   = (int*)(ws + off); off += 256 * 16 * 4;
    int* totals      = (int*)(ws + off); off += 256;
    int* slot_token  = (int*)(ws + off); off += (size_t)E_EXP * CAPE * 4;
    int* dropList    = (int*)(ws + off); off += (size_t)N_TOK * 4;
    ushort* W1T      = (ushort*)(ws + off); off += (size_t)E_EXP * D_IN * H_DIM * 2;
    ushort* W2T      = (ushort*)(ws + off); off += (size_t)E_EXP * H_DIM * O_DIM * 2;
    ushort* WgT      = (ushort*)(ws + off); off += (size_t)3 * GHID * D_IN * 2;
    ushort* xbf      = (ushort*)(ws + off); off += (size_t)N_TOK * D_IN * 2;
    const bool use_xbf = (ws_size >= off);
    if (!use_xbf) xbf = nullptr;

    hipMemsetAsync(dropCount, 0, 4, stream);
    wsplit_kernel<<<GHID, 64, 0, stream>>>(Wg1, WgT);
    cvt_transpose_kernel<D_IN, H_DIM><<<E_EXP * (D_IN/32) * (H_DIM/32), 256, 0, stream>>>(W1, W1T);
    cvt_transpose_kernel<H_DIM, O_DIM><<<E_EXP * (H_DIM/32) * (O_DIM/32), 256, 0, stream>>>(W2, W2T);
    gating_mfma_kernel<<<N_TOK / 64, 256, 0, stream>>>(x, WgT, bg1, Wg2, bg2, top_expert, xbf);
    count_kernel<<<N_TOK / 512, 256, 0, stream>>>(top_expert, blockCounts);
    scan_kernel<<<1, 64, 0, stream>>>(blockCounts, blockOffs, totals);
    scatter_kernel<<<N_TOK / 512, 64, 0, stream>>>(top_expert, blockOffs, slot_token, dropCount, dropList);
    expert_mfma_kernel<<<E_EXP * (CAPE / 64), 512, 0, stream>>>(x, xbf, W1T, b1, W2T, b2, slot_token, totals, out);
    zero_dropped_kernel<<<256, 256, 0, stream>>>(dropCount, dropList, out);
}